// Round 11
// baseline (346.523 us; speedup 1.0000x reference)
//
#include <hip/hip_runtime.h>
#include <hip/hip_bf16.h>

typedef _Float16 half4_t __attribute__((ext_vector_type(4)));
typedef _Float16 half8_t __attribute__((ext_vector_type(8)));
typedef float    float4_t __attribute__((ext_vector_type(4)));

#define MFMA32(a, b, c) __builtin_amdgcn_mfma_f32_16x16x32_f16((a), (b), (c), 0, 0, 0)

constexpr int  Bb  = 1024;
constexpr long CTX = (long)Bb * 64 * 512;      // attn offset in d_out
constexpr int  SQP = 520;                      // sQ (V^T) row stride (halves)
constexpr int  QTP = 72;                       // qT row stride (halves), kernel B
constexpr long V2OFF  = 524288;                // V2 offset into ws (halves)
constexpr long Q16OFF = V2OFF + (long)Bb * 32768;   // q16 offset (halves)
constexpr long WS_NEED = (Q16OFF + (long)Bb * 32768) * 2;  // bytes

// ---- pre-pass: pack W (f32 [e][f]) into fragment layout fp16 ----
// W2[(E*16+c)*512 + lane*8 + j] = W[E*16+(lane&15)][c*32+(lane>>4)*8+j]
__global__ void w_pack(const float* __restrict__ W, _Float16* __restrict__ W2) {
    const int t = blockIdx.x * 256 + threadIdx.x;      // 32768 threads
    const int lane = t & 63, grp = t >> 6;             // grp 0..511
    const int E = grp >> 4, c = grp & 15;
    const int r16 = lane & 15, q = lane >> 4;
    const float* src = W + (long)(E * 16 + r16) * 512 + c * 32 + q * 8;
    float4_t x = *(const float4_t*)(src);
    float4_t y = *(const float4_t*)(src + 4);
    half8_t h;
    h[0]=(_Float16)x[0]; h[1]=(_Float16)x[1]; h[2]=(_Float16)x[2]; h[3]=(_Float16)x[3];
    h[4]=(_Float16)y[0]; h[5]=(_Float16)y[1]; h[6]=(_Float16)y[2]; h[7]=(_Float16)y[3];
    *(half8_t*)(W2 + (long)t * 8) = h;
}

// ---- kernel V: V^T = q*W^T per batch, direct global A-frags (no q staging) ----
// V2[b][(gt*16+cc)*512 + lane*8 + j] (B-frag order); optional q16 fp16 copy of q.
__global__ __launch_bounds__(512, 2)
void ovo_v(const float* __restrict__ qm, const _Float16* __restrict__ W2,
           _Float16* __restrict__ V2, _Float16* __restrict__ q16, int wq16)
{
    __shared__ __align__(16) _Float16 sQ[64 * SQP];   // V^T staging; 66.6 KB

    const int t = threadIdx.x, lane = t & 63, w = t >> 6;
    const int r16 = lane & 15, q = lane >> 4;
    const long base = (long)blockIdx.x * 64 * 512;
    const float4_t zf4 = {0.f, 0.f, 0.f, 0.f};

    float4_t vacc[4][4];   // [g2][et]
    #pragma unroll
    for (int i = 0; i < 4; ++i)
        #pragma unroll
        for (int j = 0; j < 4; ++j) vacc[i][j] = zf4;

    #pragma unroll
    for (int c = 0; c < 16; ++c) {
        half8_t Aq[4], Bw[4];
        #pragma unroll
        for (int g2 = 0; g2 < 4; ++g2) {
            const float* ap = qm + base + (long)(g2 * 16 + r16) * 512 + c * 32 + q * 8;
            float4_t x = *(const float4_t*)(ap);
            float4_t y = *(const float4_t*)(ap + 4);
            half8_t h;
            h[0]=(_Float16)x[0]; h[1]=(_Float16)x[1]; h[2]=(_Float16)x[2]; h[3]=(_Float16)x[3];
            h[4]=(_Float16)y[0]; h[5]=(_Float16)y[1]; h[6]=(_Float16)y[2]; h[7]=(_Float16)y[3];
            Aq[g2] = h;
        }
        if (wq16 && (c >> 1) == w) {     // wave w persists chunks 2w, 2w+1
            #pragma unroll
            for (int g2 = 0; g2 < 4; ++g2)
                *(half8_t*)(q16 + base + (long)(g2 * 16 + r16) * 512 + c * 32 + q * 8) = Aq[g2];
        }
        #pragma unroll
        for (int et = 0; et < 4; ++et)
            Bw[et] = *(const half8_t*)(W2 + (long)((w * 4 + et) * 16 + c) * 512 + lane * 8);
        #pragma unroll
        for (int g2 = 0; g2 < 4; ++g2)
            #pragma unroll
            for (int et = 0; et < 4; ++et)
                vacc[g2][et] = MFMA32(Aq[g2], Bw[et], vacc[g2][et]);
    }

    // V^T -> LDS (D layout: row g = g2*16+q*4+r, col e = w*64+et*16+r16)
    #pragma unroll
    for (int g2 = 0; g2 < 4; ++g2)
        #pragma unroll
        for (int et = 0; et < 4; ++et)
            #pragma unroll
            for (int r = 0; r < 4; ++r)
                sQ[(g2 * 16 + q * 4 + r) * SQP + w * 64 + et * 16 + r16] =
                    (_Float16)vacc[g2][et][r];
    __syncthreads();

    // fragment-order write to V2 (1 KB linear per wave-instr)
    _Float16* vdst = V2 + (long)blockIdx.x * 32768;
    #pragma unroll
    for (int i = 0; i < 8; ++i) {
        const int grp = w * 8 + i;              // 0..63 = gt*16 + cc
        const int gt = grp >> 4, cc = grp & 15;
        half8_t hv = *(const half8_t*)(&sQ[(gt * 16 + r16) * SQP + cc * 32 + q * 8]);
        *(half8_t*)(vdst + (long)grp * 512 + lane * 8) = hv;
    }
}

// ---- kernel S: score = mean*V streamed; block = (batch, h-quarter); softmax -> attn ----
__global__ __launch_bounds__(256, 4)
void ovo_s(const float* __restrict__ o1, const float* __restrict__ o2,
           const float* __restrict__ o3, const _Float16* __restrict__ V2,
           float* __restrict__ out)
{
    __shared__ float sRed[4][16 * 68];     // 17.4 KB partial-score buffers

    const int t = threadIdx.x, lane = t & 63, w = t >> 6;   // 4 waves = 4 e-slices
    const int r16 = lane & 15, q = lane >> 4;
    const int b  = blockIdx.x >> 2;
    const int hq = blockIdx.x & 3;
    const long base = (long)b * 64 * 512;
    const long abase = base + (long)(hq * 16 + r16) * 512 + w * 128 + q * 8;
    const _Float16* vb = V2 + (long)b * 32768;
    const float4_t zf4 = {0.f, 0.f, 0.f, 0.f};

    float4_t acc0 = zf4, acc1 = zf4, acc2 = zf4, acc3 = zf4;
    float4_t a1A, b1A, a2A, b2A, a3A, b3A;
    float4_t a1B, b1B, a2B, b2B, a3B, b3B;

    #define SLOAD(S, c) do { \
        const long o_ = abase + (c) * 32; \
        a1##S = *(const float4_t*)(o1 + o_); b1##S = *(const float4_t*)(o1 + o_ + 4); \
        a2##S = *(const float4_t*)(o2 + o_); b2##S = *(const float4_t*)(o2 + o_ + 4); \
        a3##S = *(const float4_t*)(o3 + o_); b3##S = *(const float4_t*)(o3 + o_ + 4); \
    } while (0)

    #define SCOMP(S, c) do { \
        float4_t m0 = (a1##S + a2##S + a3##S) * (1.0f / 3.0f); \
        float4_t m1 = (b1##S + b2##S + b3##S) * (1.0f / 3.0f); \
        half8_t af; \
        af[0]=(_Float16)m0[0]; af[1]=(_Float16)m0[1]; af[2]=(_Float16)m0[2]; af[3]=(_Float16)m0[3]; \
        af[4]=(_Float16)m1[0]; af[5]=(_Float16)m1[1]; af[6]=(_Float16)m1[2]; af[7]=(_Float16)m1[3]; \
        half8_t bf0 = *(const half8_t*)(vb + (long)(0 * 16 + w * 4 + (c)) * 512 + lane * 8); \
        half8_t bf1 = *(const half8_t*)(vb + (long)(1 * 16 + w * 4 + (c)) * 512 + lane * 8); \
        half8_t bf2 = *(const half8_t*)(vb + (long)(2 * 16 + w * 4 + (c)) * 512 + lane * 8); \
        half8_t bf3 = *(const half8_t*)(vb + (long)(3 * 16 + w * 4 + (c)) * 512 + lane * 8); \
        acc0 = MFMA32(af, bf0, acc0); \
        acc1 = MFMA32(af, bf1, acc1); \
        acc2 = MFMA32(af, bf2, acc2); \
        acc3 = MFMA32(af, bf3, acc3); \
    } while (0)

    // 2-deep pipeline; sched_barrier(0) pins loads BEFORE compute so both
    // prefetch sets stay live in VGPRs (compiler otherwise re-serializes).
    SLOAD(A, 0); SLOAD(B, 1);
    __builtin_amdgcn_sched_barrier(0);
    SCOMP(A, 0); SLOAD(A, 2);
    __builtin_amdgcn_sched_barrier(0);
    SCOMP(B, 1); SLOAD(B, 3);
    __builtin_amdgcn_sched_barrier(0);
    SCOMP(A, 2);
    SCOMP(B, 3);

    // partials: sRed[w][h*68 + g], h=(q*4+r), g=gt*16+r16
    #pragma unroll
    for (int r = 0; r < 4; ++r) {
        sRed[w][(q * 4 + r) * 68 +  0 + r16] = acc0[r];
        sRed[w][(q * 4 + r) * 68 + 16 + r16] = acc1[r];
        sRed[w][(q * 4 + r) * 68 + 32 + r16] = acc2[r];
        sRed[w][(q * 4 + r) * 68 + 48 + r16] = acc3[r];
    }
    __syncthreads();
    if (w == 0) {
        for (int i = 0; i < 17; ++i)
            sRed[0][lane + i * 64] += sRed[2][lane + i * 64];
    }
    if (w == 1) {
        for (int i = 0; i < 17; ++i)
            sRed[1][lane + i * 64] += sRed[3][lane + i * 64];
    }
    __syncthreads();
    if (w == 0) {
        for (int i = 0; i < 17; ++i)
            sRed[0][lane + i * 64] += sRed[1][lane + i * 64];
    }
    __syncthreads();

    // softmax over g (wave 0: 16 rows, 4 lanes/row)
    if (w == 0) {
        const float* srow = &sRed[0][r16 * 68 + q * 16];
        float v[16];
        float mx = -1e30f;
        #pragma unroll
        for (int i = 0; i < 16; ++i) { v[i] = srow[i]; mx = fmaxf(mx, v[i]); }
        mx = fmaxf(mx, __shfl_xor(mx, 16));
        mx = fmaxf(mx, __shfl_xor(mx, 32));
        float sum = 0.f;
        #pragma unroll
        for (int i = 0; i < 16; ++i) { v[i] = __expf(v[i] - mx); sum += v[i]; }
        sum += __shfl_xor(sum, 16);
        sum += __shfl_xor(sum, 32);
        const float inv = 1.0f / sum;
        float* aout = out + CTX + ((long)b * 64 + hq * 16 + r16) * 64 + q * 16;
        #pragma unroll
        for (int i = 0; i < 16; ++i) aout[i] = v[i] * inv;
    }
}

// ---- kernel B (fp16 q): context = attn @ q16 ----
__global__ __launch_bounds__(256, 4)
void ovo_ctx16(const _Float16* __restrict__ q16, const float* __restrict__ out_attn,
               float* __restrict__ out)
{
    __shared__ __align__(16) _Float16 qT[2][64 * QTP];   // q^T chunk [e][g]  36 KB

    const int t = threadIdx.x, lane = t & 63, w = t >> 6;
    const int r16 = lane & 15, q = lane >> 4;
    const long b = blockIdx.x;
    const long base = b * 64 * 512;
    const float4_t zf4 = {0.f, 0.f, 0.f, 0.f};

    const float* ap = out_attn + (b * 64 + w * 16 + r16) * 64 + q * 8;
    half8_t pA0, pA1;
    {
        float4_t x = *(const float4_t*)(ap + 0),  y = *(const float4_t*)(ap + 4);
        pA0[0]=(_Float16)x[0]; pA0[1]=(_Float16)x[1]; pA0[2]=(_Float16)x[2]; pA0[3]=(_Float16)x[3];
        pA0[4]=(_Float16)y[0]; pA0[5]=(_Float16)y[1]; pA0[6]=(_Float16)y[2]; pA0[7]=(_Float16)y[3];
        float4_t z = *(const float4_t*)(ap + 32), u = *(const float4_t*)(ap + 36);
        pA1[0]=(_Float16)z[0]; pA1[1]=(_Float16)z[1]; pA1[2]=(_Float16)z[2]; pA1[3]=(_Float16)z[3];
        pA1[4]=(_Float16)u[0]; pA1[5]=(_Float16)u[1]; pA1[6]=(_Float16)u[2]; pA1[7]=(_Float16)u[3];
    }

    const int sg = t & 63, se = (t >> 6) * 16;
    const _Float16* qsrc = q16 + base + (long)sg * 512 + se;
    half8_t rA0, rA1, rB0, rB1;

    #define QLOAD16(R, c) do { \
        R##0 = *(const half8_t*)(qsrc + (c) * 64); \
        R##1 = *(const half8_t*)(qsrc + (c) * 64 + 8); \
    } while (0)
    #define QCOMMIT16(R, buf) do { \
        _Pragma("unroll") \
        for (int jj = 0; jj < 8; ++jj) qT[buf][(se + jj) * QTP + sg] = R##0[jj]; \
        _Pragma("unroll") \
        for (int jj = 0; jj < 8; ++jj) qT[buf][(se + 8 + jj) * QTP + sg] = R##1[jj]; \
    } while (0)
    #define BCOMP(c, buf) do { \
        _Pragma("unroll") \
        for (int et = 0; et < 4; ++et) { \
            half8_t b0 = *(const half8_t*)(&qT[buf][(et * 16 + r16) * QTP + q * 8]); \
            half8_t b1 = *(const half8_t*)(&qT[buf][(et * 16 + r16) * QTP + 32 + q * 8]); \
            float4_t acc = MFMA32(pA0, b0, zf4); \
            acc = MFMA32(pA1, b1, acc); \
            _Pragma("unroll") \
            for (int rr = 0; rr < 4; ++rr) \
                out[(b * 64 + w * 16 + q * 4 + rr) * 512 + (c) * 64 + et * 16 + r16] = acc[rr]; \
        } \
    } while (0)

    QLOAD16(rA, 0);
    QCOMMIT16(rA, 0);
    __syncthreads();
    #pragma unroll
    for (int cc = 0; cc < 8; cc += 2) {
        QLOAD16(rB, cc + 1);
        BCOMP(cc, 0);
        QCOMMIT16(rB, 1);
        __syncthreads();
        if (cc + 2 < 8) QLOAD16(rA, cc + 2);
        BCOMP(cc + 1, 1);
        if (cc + 2 < 8) QCOMMIT16(rA, 0);
        __syncthreads();
    }
}

// ---- kernel B (f32 fallback, identical to R10) ----
__global__ __launch_bounds__(256, 4)
void ovo_ctx(const float* __restrict__ qm, const float* __restrict__ out_attn,
             float* __restrict__ out)
{
    __shared__ __align__(16) _Float16 qT[2][64 * QTP];

    const int t = threadIdx.x, lane = t & 63, w = t >> 6;
    const int r16 = lane & 15, q = lane >> 4;
    const long b = blockIdx.x;
    const long base = b * 64 * 512;
    const float4_t zf4 = {0.f, 0.f, 0.f, 0.f};

    const float* ap = out_attn + (b * 64 + w * 16 + r16) * 64 + q * 8;
    half8_t pA0, pA1;
    {
        float4_t x = *(const float4_t*)(ap + 0),  y = *(const float4_t*)(ap + 4);
        pA0[0]=(_Float16)x[0]; pA0[1]=(_Float16)x[1]; pA0[2]=(_Float16)x[2]; pA0[3]=(_Float16)x[3];
        pA0[4]=(_Float16)y[0]; pA0[5]=(_Float16)y[1]; pA0[6]=(_Float16)y[2]; pA0[7]=(_Float16)y[3];
        float4_t z = *(const float4_t*)(ap + 32), u = *(const float4_t*)(ap + 36);
        pA1[0]=(_Float16)z[0]; pA1[1]=(_Float16)z[1]; pA1[2]=(_Float16)z[2]; pA1[3]=(_Float16)z[3];
        pA1[4]=(_Float16)u[0]; pA1[5]=(_Float16)u[1]; pA1[6]=(_Float16)u[2]; pA1[7]=(_Float16)u[3];
    }

    const int sg = t & 63, se = (t >> 6) * 16;
    const float* qsrc = qm + base + (long)sg * 512 + se;
    float4_t rA[4], rB[4];

    #define QLOAD(R, c) do { \
        _Pragma("unroll") \
        for (int i = 0; i < 4; ++i) R[i] = *(const float4_t*)(qsrc + (c) * 64 + i * 4); \
    } while (0)
    #define QCOMMIT(R, buf) do { \
        _Pragma("unroll") \
        for (int i = 0; i < 4; ++i) \
            _Pragma("unroll") \
            for (int jj = 0; jj < 4; ++jj) \
                qT[buf][(se + i * 4 + jj) * QTP + sg] = (_Float16)R[i][jj]; \
    } while (0)

    QLOAD(rA, 0);
    QCOMMIT(rA, 0);
    __syncthreads();
    #pragma unroll
    for (int cc = 0; cc < 8; cc += 2) {
        QLOAD(rB, cc + 1);
        BCOMP(cc, 0);
        QCOMMIT(rB, 1);
        __syncthreads();
        if (cc + 2 < 8) QLOAD(rA, cc + 2);
        BCOMP(cc + 1, 1);
        if (cc + 2 < 8) QCOMMIT(rA, 0);
        __syncthreads();
    }
}

extern "C" void kernel_launch(void* const* d_in, const int* in_sizes, int n_in,
                              void* d_out, int out_size, void* d_ws, size_t ws_size,
                              hipStream_t stream) {
    const float* o1 = (const float*)d_in[0];
    const float* o2 = (const float*)d_in[1];
    const float* o3 = (const float*)d_in[2];
    const float* qm = (const float*)d_in[3];
    const float* W  = (const float*)d_in[4];
    float* out = (float*)d_out;
    _Float16* W2  = (_Float16*)d_ws;                 // 1 MB  fragment-layout fp16 W
    _Float16* V2  = (_Float16*)d_ws + V2OFF;         // 67 MB fragment-layout fp16 V
    _Float16* q16 = (_Float16*)d_ws + Q16OFF;        // 67 MB fp16 copy of q

    const int use_q16 = (ws_size >= (size_t)WS_NEED) ? 1 : 0;

    w_pack<<<dim3(128), dim3(256), 0, stream>>>(W, W2);
    ovo_v<<<dim3(Bb), dim3(512), 0, stream>>>(qm, W2, V2, q16, use_q16);
    ovo_s<<<dim3(Bb * 4), dim3(256), 0, stream>>>(o1, o2, o3, V2, out);
    if (use_q16)
        ovo_ctx16<<<dim3(Bb), dim3(256), 0, stream>>>(q16, out + CTX, out);
    else
        ovo_ctx<<<dim3(Bb), dim3(256), 0, stream>>>(qm, out + CTX, out);
}

// Round 12
// 259.445 us; speedup vs baseline: 1.3356x; 1.3356x over previous
//
#include <hip/hip_runtime.h>
#include <hip/hip_bf16.h>

typedef _Float16 half4_t __attribute__((ext_vector_type(4)));
typedef _Float16 half8_t __attribute__((ext_vector_type(8)));
typedef float    float4_t __attribute__((ext_vector_type(4)));

#define MFMA32(a, b, c) __builtin_amdgcn_mfma_f32_16x16x32_f16((a), (b), (c), 0, 0, 0)

constexpr int  Bb  = 1024;
constexpr long CTX = (long)Bb * 64 * 512;      // attn offset in d_out
constexpr int  SQP = 520;                      // sQ (q / V^T) row stride (halves)
constexpr int  QTP = 72;                       // qT row stride (halves), kernel B
constexpr long V2OFF = 524288;                 // V2 offset into ws (halves)

// ---- pre-pass: pack W (f32 [e][f]) into fragment layout fp16 ----
// W2[(E*16+c)*512 + lane*8 + j] = W[E*16+(lane&15)][c*32+(lane>>4)*8+j]
__global__ void w_pack(const float* __restrict__ W, _Float16* __restrict__ W2) {
    const int t = blockIdx.x * 256 + threadIdx.x;      // 32768 threads
    const int lane = t & 63, grp = t >> 6;             // grp 0..511
    const int E = grp >> 4, c = grp & 15;
    const int r16 = lane & 15, q = lane >> 4;
    const float* src = W + (long)(E * 16 + r16) * 512 + c * 32 + q * 8;
    float4_t x = *(const float4_t*)(src);
    float4_t y = *(const float4_t*)(src + 4);
    half8_t h;
    h[0]=(_Float16)x[0]; h[1]=(_Float16)x[1]; h[2]=(_Float16)x[2]; h[3]=(_Float16)x[3];
    h[4]=(_Float16)y[0]; h[5]=(_Float16)y[1]; h[6]=(_Float16)y[2]; h[7]=(_Float16)y[3];
    *(half8_t*)(W2 + (long)t * 8) = h;
}

// ---- kernel V (R10 form): stage q->LDS, V^T = q*W^T, write V2 in B-frag order ----
__global__ __launch_bounds__(512, 3)
void ovo_v(const float* __restrict__ qm, const _Float16* __restrict__ W2,
           _Float16* __restrict__ V2)
{
    __shared__ __align__(16) _Float16 sQ[64 * SQP];   // q fp16, then V^T; 66.6 KB

    const int t = threadIdx.x, lane = t & 63, w = t >> 6;
    const int r16 = lane & 15, q = lane >> 4;
    const long base = (long)blockIdx.x * 64 * 512;
    const float4_t zf4 = {0.f, 0.f, 0.f, 0.f};

    // stage q fp16, flat-linear
    {
        const long qb = base + (long)t * 4;
        #pragma unroll
        for (int k = 0; k < 16; ++k) {
            float4_t v = *(const float4_t*)(qm + qb + (long)k * 2048);
            half4_t h;
            h[0]=(_Float16)v[0]; h[1]=(_Float16)v[1]; h[2]=(_Float16)v[2]; h[3]=(_Float16)v[3];
            *(half4_t*)(&sQ[(k * 4 + (t >> 7)) * SQP + (t & 127) * 4]) = h;
        }
    }
    __syncthreads();

    // V^T[g][e] = sum_f q[g,f]*W[e,f]; wave w owns e-slice [64w, 64w+64)
    float4_t vacc[4][4];   // [g2][et]
    #pragma unroll
    for (int i = 0; i < 4; ++i)
        #pragma unroll
        for (int j = 0; j < 4; ++j) vacc[i][j] = zf4;

    #pragma unroll
    for (int c = 0; c < 16; ++c) {
        half8_t Aq[4], Bw[4];
        #pragma unroll
        for (int g2 = 0; g2 < 4; ++g2)
            Aq[g2] = *(const half8_t*)(&sQ[(g2 * 16 + r16) * SQP + c * 32 + q * 8]);
        #pragma unroll
        for (int et = 0; et < 4; ++et)
            Bw[et] = *(const half8_t*)(W2 + (long)((w * 4 + et) * 16 + c) * 512 + lane * 8);
        #pragma unroll
        for (int g2 = 0; g2 < 4; ++g2)
            #pragma unroll
            for (int et = 0; et < 4; ++et)
                vacc[g2][et] = MFMA32(Aq[g2], Bw[et], vacc[g2][et]);
    }
    __syncthreads();                       // q dead

    // V^T overwrites sQ
    #pragma unroll
    for (int g2 = 0; g2 < 4; ++g2)
        #pragma unroll
        for (int et = 0; et < 4; ++et)
            #pragma unroll
            for (int r = 0; r < 4; ++r)
                sQ[(g2 * 16 + q * 4 + r) * SQP + w * 64 + et * 16 + r16] =
                    (_Float16)vacc[g2][et][r];
    __syncthreads();

    // fragment-order write to V2 (1 KB linear per wave-instr)
    _Float16* vdst = V2 + (long)blockIdx.x * 32768;
    #pragma unroll
    for (int i = 0; i < 8; ++i) {
        const int grp = w * 8 + i;              // 0..63 = gt*16 + cc
        const int gt = grp >> 4, cc = grp & 15;
        half8_t hv = *(const half8_t*)(&sQ[(gt * 16 + r16) * SQP + cc * 32 + q * 8]);
        *(half8_t*)(vdst + (long)grp * 512 + lane * 8) = hv;
    }
}

// ---- kernel S: score = mean*V streamed; XCD swizzle + chunk rotation ----
__global__ __launch_bounds__(256, 4)
void ovo_s(const float* __restrict__ o1, const float* __restrict__ o2,
           const float* __restrict__ o3, const _Float16* __restrict__ V2,
           float* __restrict__ out)
{
    __shared__ float sRed[4][16 * 68];     // 17.4 KB partial-score buffers

    const int t = threadIdx.x, lane = t & 63, w = t >> 6;   // 4 waves = 4 e-slices
    const int r16 = lane & 15, q = lane >> 4;

    // XCD-chunked swizzle: the 4 hq-blocks of a batch sit 8 apart in dispatch
    // order (same XCD, co-resident -> V2 L2 reuse); each XCD owns a contiguous
    // batch range.
    const int l = blockIdx.x;
    const int xcd = l & 7, m = l >> 3;
    const int b  = xcd * 128 + (m >> 2);
    const int hq = m & 3;
    const int rot = (b ^ hq) & 3;          // chunk-walk phase rotation
    const int c0 = rot, c1 = rot ^ 1, c2 = rot ^ 2, c3 = rot ^ 3;

    const long base = (long)b * 64 * 512;
    const long abase = base + (long)(hq * 16 + r16) * 512 + w * 128 + q * 8;
    const _Float16* vb = V2 + (long)b * 32768;
    const float4_t zf4 = {0.f, 0.f, 0.f, 0.f};

    float4_t acc0 = zf4, acc1 = zf4, acc2 = zf4, acc3 = zf4;
    float4_t a1A, b1A, a2A, b2A, a3A, b3A;
    float4_t a1B, b1B, a2B, b2B, a3B, b3B;

    #define SLOAD(S, c) do { \
        const long o_ = abase + (c) * 32; \
        a1##S = *(const float4_t*)(o1 + o_); b1##S = *(const float4_t*)(o1 + o_ + 4); \
        a2##S = *(const float4_t*)(o2 + o_); b2##S = *(const float4_t*)(o2 + o_ + 4); \
        a3##S = *(const float4_t*)(o3 + o_); b3##S = *(const float4_t*)(o3 + o_ + 4); \
    } while (0)

    #define SCOMP(S, c) do { \
        float4_t m0 = (a1##S + a2##S + a3##S) * (1.0f / 3.0f); \
        float4_t m1 = (b1##S + b2##S + b3##S) * (1.0f / 3.0f); \
        half8_t af; \
        af[0]=(_Float16)m0[0]; af[1]=(_Float16)m0[1]; af[2]=(_Float16)m0[2]; af[3]=(_Float16)m0[3]; \
        af[4]=(_Float16)m1[0]; af[5]=(_Float16)m1[1]; af[6]=(_Float16)m1[2]; af[7]=(_Float16)m1[3]; \
        half8_t bf0 = *(const half8_t*)(vb + (long)(0 * 16 + w * 4 + (c)) * 512 + lane * 8); \
        half8_t bf1 = *(const half8_t*)(vb + (long)(1 * 16 + w * 4 + (c)) * 512 + lane * 8); \
        half8_t bf2 = *(const half8_t*)(vb + (long)(2 * 16 + w * 4 + (c)) * 512 + lane * 8); \
        half8_t bf3 = *(const half8_t*)(vb + (long)(3 * 16 + w * 4 + (c)) * 512 + lane * 8); \
        acc0 = MFMA32(af, bf0, acc0); \
        acc1 = MFMA32(af, bf1, acc1); \
        acc2 = MFMA32(af, bf2, acc2); \
        acc3 = MFMA32(af, bf3, acc3); \
    } while (0)

    // 2-deep pipeline; sched_barrier(0) pins loads ahead of compute.
    SLOAD(A, c0); SLOAD(B, c1);
    __builtin_amdgcn_sched_barrier(0);
    SCOMP(A, c0); SLOAD(A, c2);
    __builtin_amdgcn_sched_barrier(0);
    SCOMP(B, c1); SLOAD(B, c3);
    __builtin_amdgcn_sched_barrier(0);
    SCOMP(A, c2);
    SCOMP(B, c3);

    // partials: sRed[w][h*68 + g], h=(q*4+r), g=gt*16+r16
    #pragma unroll
    for (int r = 0; r < 4; ++r) {
        sRed[w][(q * 4 + r) * 68 +  0 + r16] = acc0[r];
        sRed[w][(q * 4 + r) * 68 + 16 + r16] = acc1[r];
        sRed[w][(q * 4 + r) * 68 + 32 + r16] = acc2[r];
        sRed[w][(q * 4 + r) * 68 + 48 + r16] = acc3[r];
    }
    __syncthreads();
    if (w == 0) {
        for (int i = 0; i < 17; ++i)
            sRed[0][lane + i * 64] += sRed[2][lane + i * 64];
    }
    if (w == 1) {
        for (int i = 0; i < 17; ++i)
            sRed[1][lane + i * 64] += sRed[3][lane + i * 64];
    }
    __syncthreads();
    if (w == 0) {
        for (int i = 0; i < 17; ++i)
            sRed[0][lane + i * 64] += sRed[1][lane + i * 64];
    }
    __syncthreads();

    // softmax over g (wave 0: 16 rows, 4 lanes/row)
    if (w == 0) {
        const float* srow = &sRed[0][r16 * 68 + q * 16];
        float v[16];
        float mx = -1e30f;
        #pragma unroll
        for (int i = 0; i < 16; ++i) { v[i] = srow[i]; mx = fmaxf(mx, v[i]); }
        mx = fmaxf(mx, __shfl_xor(mx, 16));
        mx = fmaxf(mx, __shfl_xor(mx, 32));
        float sum = 0.f;
        #pragma unroll
        for (int i = 0; i < 16; ++i) { v[i] = __expf(v[i] - mx); sum += v[i]; }
        sum += __shfl_xor(sum, 16);
        sum += __shfl_xor(sum, 32);
        const float inv = 1.0f / sum;
        float* aout = out + CTX + ((long)b * 64 + hq * 16 + r16) * 64 + q * 16;
        #pragma unroll
        for (int i = 0; i < 16; ++i) aout[i] = v[i] * inv;
    }
}

// ---- kernel B: context = attn @ q (R10 form) ----
__global__ __launch_bounds__(256, 4)
void ovo_ctx(const float* __restrict__ qm, const float* __restrict__ out_attn,
             float* __restrict__ out)
{
    __shared__ __align__(16) _Float16 qT[2][64 * QTP];   // q^T chunk [e][g]  36 KB

    const int t = threadIdx.x, lane = t & 63, w = t >> 6;
    const int r16 = lane & 15, q = lane >> 4;
    const long b = blockIdx.x;
    const long base = b * 64 * 512;
    const float4_t zf4 = {0.f, 0.f, 0.f, 0.f};

    const float* ap = out_attn + (b * 64 + w * 16 + r16) * 64 + q * 8;
    half8_t pA0, pA1;
    {
        float4_t x = *(const float4_t*)(ap + 0),  y = *(const float4_t*)(ap + 4);
        pA0[0]=(_Float16)x[0]; pA0[1]=(_Float16)x[1]; pA0[2]=(_Float16)x[2]; pA0[3]=(_Float16)x[3];
        pA0[4]=(_Float16)y[0]; pA0[5]=(_Float16)y[1]; pA0[6]=(_Float16)y[2]; pA0[7]=(_Float16)y[3];
        float4_t z = *(const float4_t*)(ap + 32), u = *(const float4_t*)(ap + 36);
        pA1[0]=(_Float16)z[0]; pA1[1]=(_Float16)z[1]; pA1[2]=(_Float16)z[2]; pA1[3]=(_Float16)z[3];
        pA1[4]=(_Float16)u[0]; pA1[5]=(_Float16)u[1]; pA1[6]=(_Float16)u[2]; pA1[7]=(_Float16)u[3];
    }

    const int sg = t & 63, se = (t >> 6) * 16;
    const float* qsrc = qm + base + (long)sg * 512 + se;
    float4_t rA[4], rB[4];

    #define QLOAD(R, c) do { \
        _Pragma("unroll") \
        for (int i = 0; i < 4; ++i) R[i] = *(const float4_t*)(qsrc + (c) * 64 + i * 4); \
    } while (0)
    #define QCOMMIT(R, buf) do { \
        _Pragma("unroll") \
        for (int i = 0; i < 4; ++i) \
            _Pragma("unroll") \
            for (int jj = 0; jj < 4; ++jj) \
                qT[buf][(se + i * 4 + jj) * QTP + sg] = (_Float16)R[i][jj]; \
    } while (0)
    #define BCOMP(c, buf) do { \
        _Pragma("unroll") \
        for (int et = 0; et < 4; ++et) { \
            half8_t b0 = *(const half8_t*)(&qT[buf][(et * 16 + r16) * QTP + q * 8]); \
            half8_t b1 = *(const half8_t*)(&qT[buf][(et * 16 + r16) * QTP + 32 + q * 8]); \
            float4_t acc = MFMA32(pA0, b0, zf4); \
            acc = MFMA32(pA1, b1, acc); \
            _Pragma("unroll") \
            for (int rr = 0; rr < 4; ++rr) \
                out[(b * 64 + w * 16 + q * 4 + rr) * 512 + (c) * 64 + et * 16 + r16] = acc[rr]; \
        } \
    } while (0)

    QLOAD(rA, 0);
    QCOMMIT(rA, 0);
    __syncthreads();
    #pragma unroll
    for (int cc = 0; cc < 8; cc += 2) {
        QLOAD(rB, cc + 1);
        BCOMP(cc, 0);
        QCOMMIT(rB, 1);
        __syncthreads();
        if (cc + 2 < 8) QLOAD(rA, cc + 2);
        BCOMP(cc + 1, 1);
        if (cc + 2 < 8) QCOMMIT(rA, 0);
        __syncthreads();
    }
}

extern "C" void kernel_launch(void* const* d_in, const int* in_sizes, int n_in,
                              void* d_out, int out_size, void* d_ws, size_t ws_size,
                              hipStream_t stream) {
    const float* o1 = (const float*)d_in[0];
    const float* o2 = (const float*)d_in[1];
    const float* o3 = (const float*)d_in[2];
    const float* qm = (const float*)d_in[3];
    const float* W  = (const float*)d_in[4];
    float* out = (float*)d_out;
    _Float16* W2 = (_Float16*)d_ws;                 // 1 MB  fragment-layout fp16 W
    _Float16* V2 = (_Float16*)d_ws + V2OFF;         // 67 MB fragment-layout fp16 V

    w_pack<<<dim3(128), dim3(256), 0, stream>>>(W, W2);
    ovo_v<<<dim3(Bb), dim3(512), 0, stream>>>(qm, W2, V2);
    ovo_s<<<dim3(Bb * 4), dim3(256), 0, stream>>>(o1, o2, o3, V2, out);
    ovo_ctx<<<dim3(Bb), dim3(256), 0, stream>>>(qm, out + CTX, out);
}

// Round 13
// 259.094 us; speedup vs baseline: 1.3374x; 1.0014x over previous
//
#include <hip/hip_runtime.h>
#include <hip/hip_bf16.h>

typedef _Float16 half4_t __attribute__((ext_vector_type(4)));
typedef _Float16 half8_t __attribute__((ext_vector_type(8)));
typedef float    float4_t __attribute__((ext_vector_type(4)));

#define MFMA32(a, b, c) __builtin_amdgcn_mfma_f32_16x16x32_f16((a), (b), (c), 0, 0, 0)

constexpr int  Bb  = 1024;
constexpr long CTX = (long)Bb * 64 * 512;      // attn offset in d_out
constexpr int  SQP = 520;                      // sQ (q / V^T) row stride (halves)
constexpr int  SMP = 520;                      // sM row stride (halves)
constexpr int  QTP = 72;                       // qT row stride (halves), kernel B
constexpr long V2OFF = 524288;                 // V2 offset into ws (halves)

// ---- pre-pass: pack W (f32 [e][f]) into fragment layout fp16 ----
// W2[(E*16+c)*512 + lane*8 + j] = W[E*16+(lane&15)][c*32+(lane>>4)*8+j]
__global__ void w_pack(const float* __restrict__ W, _Float16* __restrict__ W2) {
    const int t = blockIdx.x * 256 + threadIdx.x;      // 32768 threads
    const int lane = t & 63, grp = t >> 6;             // grp 0..511
    const int E = grp >> 4, c = grp & 15;
    const int r16 = lane & 15, q = lane >> 4;
    const float* src = W + (long)(E * 16 + r16) * 512 + c * 32 + q * 8;
    float4_t x = *(const float4_t*)(src);
    float4_t y = *(const float4_t*)(src + 4);
    half8_t h;
    h[0]=(_Float16)x[0]; h[1]=(_Float16)x[1]; h[2]=(_Float16)x[2]; h[3]=(_Float16)x[3];
    h[4]=(_Float16)y[0]; h[5]=(_Float16)y[1]; h[6]=(_Float16)y[2]; h[7]=(_Float16)y[3];
    *(half8_t*)(W2 + (long)t * 8) = h;
}

// ---- kernel V: stage q->LDS, V^T = q*W^T, write V2 in B-frag order ----
__global__ __launch_bounds__(512, 3)
void ovo_v(const float* __restrict__ qm, const _Float16* __restrict__ W2,
           _Float16* __restrict__ V2)
{
    __shared__ __align__(16) _Float16 sQ[64 * SQP];   // q fp16, then V^T; 66.6 KB

    const int t = threadIdx.x, lane = t & 63, w = t >> 6;
    const int r16 = lane & 15, q = lane >> 4;
    const long base = (long)blockIdx.x * 64 * 512;
    const float4_t zf4 = {0.f, 0.f, 0.f, 0.f};

    // stage q fp16, flat-linear
    {
        const long qb = base + (long)t * 4;
        #pragma unroll
        for (int k = 0; k < 16; ++k) {
            float4_t v = *(const float4_t*)(qm + qb + (long)k * 2048);
            half4_t h;
            h[0]=(_Float16)v[0]; h[1]=(_Float16)v[1]; h[2]=(_Float16)v[2]; h[3]=(_Float16)v[3];
            *(half4_t*)(&sQ[(k * 4 + (t >> 7)) * SQP + (t & 127) * 4]) = h;
        }
    }
    __syncthreads();

    float4_t vacc[4][4];   // [g2][et]
    #pragma unroll
    for (int i = 0; i < 4; ++i)
        #pragma unroll
        for (int j = 0; j < 4; ++j) vacc[i][j] = zf4;

    #pragma unroll
    for (int c = 0; c < 16; ++c) {
        half8_t Aq[4], Bw[4];
        #pragma unroll
        for (int g2 = 0; g2 < 4; ++g2)
            Aq[g2] = *(const half8_t*)(&sQ[(g2 * 16 + r16) * SQP + c * 32 + q * 8]);
        #pragma unroll
        for (int et = 0; et < 4; ++et)
            Bw[et] = *(const half8_t*)(W2 + (long)((w * 4 + et) * 16 + c) * 512 + lane * 8);
        #pragma unroll
        for (int g2 = 0; g2 < 4; ++g2)
            #pragma unroll
            for (int et = 0; et < 4; ++et)
                vacc[g2][et] = MFMA32(Aq[g2], Bw[et], vacc[g2][et]);
    }
    __syncthreads();                       // q dead

    #pragma unroll
    for (int g2 = 0; g2 < 4; ++g2)
        #pragma unroll
        for (int et = 0; et < 4; ++et)
            #pragma unroll
            for (int r = 0; r < 4; ++r)
                sQ[(g2 * 16 + q * 4 + r) * SQP + w * 64 + et * 16 + r16] =
                    (_Float16)vacc[g2][et][r];
    __syncthreads();

    _Float16* vdst = V2 + (long)blockIdx.x * 32768;
    #pragma unroll
    for (int i = 0; i < 8; ++i) {
        const int grp = w * 8 + i;              // 0..63 = gt*16 + cc
        const int gt = grp >> 4, cc = grp & 15;
        half8_t hv = *(const half8_t*)(&sQ[(gt * 16 + r16) * SQP + cc * 32 + q * 8]);
        *(half8_t*)(vdst + (long)grp * 512 + lane * 8) = hv;
    }
}

// ---- kernel S: linear o-stage -> LDS mean -> fragment MFMA vs V2; softmax ----
__global__ __launch_bounds__(256, 4)
void ovo_s(const float* __restrict__ o1, const float* __restrict__ o2,
           const float* __restrict__ o3, const _Float16* __restrict__ V2,
           float* __restrict__ out)
{
    __shared__ __align__(16) _Float16 sM[16 * SMP];   // mean chunk fp16; 16.6 KB
    __shared__ float sRed[4][16 * 68];                // 17.4 KB partials

    const int t = threadIdx.x, lane = t & 63, w = t >> 6;   // 4 waves = 4 e-slices
    const int r16 = lane & 15, q = lane >> 4;

    // XCD-chunked swizzle (V2 L2 reuse: 4 hq-blocks of a batch co-resident)
    const int l = blockIdx.x;
    const int xcd = l & 7, m = l >> 3;
    const int b  = xcd * 128 + (m >> 2);
    const int hq = m & 3;

    const long cbase = (long)b * 32768 + (long)hq * 8192;   // floats
    const _Float16* vb = V2 + (long)b * 32768;
    const float4_t zf4 = {0.f, 0.f, 0.f, 0.f};

    // ---- linear stage: 1 KB-contiguous wave reads, two 12-load groups ----
    // chunk = 16 rows x 512 f32; float4 idx = i*256 + t -> row=(i*2+(t>>7)), col=(t&127)*4
    const float* p1 = o1 + cbase + t * 4;
    const float* p2 = o2 + cbase + t * 4;
    const float* p3 = o3 + cbase + t * 4;
    const int srow0 = t >> 7, scol = (t & 127) * 4;

    {
        float4_t A1[4], A2[4], A3[4];
        #pragma unroll
        for (int i = 0; i < 4; ++i) A1[i] = *(const float4_t*)(p1 + i * 1024);
        #pragma unroll
        for (int i = 0; i < 4; ++i) A2[i] = *(const float4_t*)(p2 + i * 1024);
        #pragma unroll
        for (int i = 0; i < 4; ++i) A3[i] = *(const float4_t*)(p3 + i * 1024);
        #pragma unroll
        for (int i = 0; i < 4; ++i) {
            float4_t mv = (A1[i] + A2[i] + A3[i]) * (1.0f / 3.0f);
            half4_t h;
            h[0]=(_Float16)mv[0]; h[1]=(_Float16)mv[1]; h[2]=(_Float16)mv[2]; h[3]=(_Float16)mv[3];
            *(half4_t*)(&sM[(i * 2 + srow0) * SMP + scol]) = h;
        }
        float4_t B1[4], B2[4], B3[4];
        #pragma unroll
        for (int i = 0; i < 4; ++i) B1[i] = *(const float4_t*)(p1 + (i + 4) * 1024);
        #pragma unroll
        for (int i = 0; i < 4; ++i) B2[i] = *(const float4_t*)(p2 + (i + 4) * 1024);
        #pragma unroll
        for (int i = 0; i < 4; ++i) B3[i] = *(const float4_t*)(p3 + (i + 4) * 1024);
        #pragma unroll
        for (int i = 0; i < 4; ++i) {
            float4_t mv = (B1[i] + B2[i] + B3[i]) * (1.0f / 3.0f);
            half4_t h;
            h[0]=(_Float16)mv[0]; h[1]=(_Float16)mv[1]; h[2]=(_Float16)mv[2]; h[3]=(_Float16)mv[3];
            *(half4_t*)(&sM[((i + 4) * 2 + srow0) * SMP + scol]) = h;
        }
    }
    __syncthreads();

    // ---- score: wave w owns e-slice [w*128, w*128+128) ----
    float4_t acc0 = zf4, acc1 = zf4, acc2 = zf4, acc3 = zf4;

    #define SCOMP(c) do { \
        half8_t af = *(const half8_t*)(&sM[r16 * SMP + w * 128 + (c) * 32 + q * 8]); \
        half8_t bf0 = *(const half8_t*)(vb + (long)( 0 + w * 4 + (c)) * 512 + lane * 8); \
        half8_t bf1 = *(const half8_t*)(vb + (long)(16 + w * 4 + (c)) * 512 + lane * 8); \
        half8_t bf2 = *(const half8_t*)(vb + (long)(32 + w * 4 + (c)) * 512 + lane * 8); \
        half8_t bf3 = *(const half8_t*)(vb + (long)(48 + w * 4 + (c)) * 512 + lane * 8); \
        acc0 = MFMA32(af, bf0, acc0); \
        acc1 = MFMA32(af, bf1, acc1); \
        acc2 = MFMA32(af, bf2, acc2); \
        acc3 = MFMA32(af, bf3, acc3); \
    } while (0)

    SCOMP(0); SCOMP(1); SCOMP(2); SCOMP(3);

    // partials: sRed[w][h*68 + g], h=(q*4+r), g=gt*16+r16
    #pragma unroll
    for (int r = 0; r < 4; ++r) {
        sRed[w][(q * 4 + r) * 68 +  0 + r16] = acc0[r];
        sRed[w][(q * 4 + r) * 68 + 16 + r16] = acc1[r];
        sRed[w][(q * 4 + r) * 68 + 32 + r16] = acc2[r];
        sRed[w][(q * 4 + r) * 68 + 48 + r16] = acc3[r];
    }
    __syncthreads();
    if (w == 0) {
        for (int i = 0; i < 17; ++i)
            sRed[0][lane + i * 64] += sRed[2][lane + i * 64];
    }
    if (w == 1) {
        for (int i = 0; i < 17; ++i)
            sRed[1][lane + i * 64] += sRed[3][lane + i * 64];
    }
    __syncthreads();
    if (w == 0) {
        for (int i = 0; i < 17; ++i)
            sRed[0][lane + i * 64] += sRed[1][lane + i * 64];
    }
    __syncthreads();

    // softmax over g (wave 0: 16 rows, 4 lanes/row)
    if (w == 0) {
        const float* srow = &sRed[0][r16 * 68 + q * 16];
        float v[16];
        float mx = -1e30f;
        #pragma unroll
        for (int i = 0; i < 16; ++i) { v[i] = srow[i]; mx = fmaxf(mx, v[i]); }
        mx = fmaxf(mx, __shfl_xor(mx, 16));
        mx = fmaxf(mx, __shfl_xor(mx, 32));
        float sum = 0.f;
        #pragma unroll
        for (int i = 0; i < 16; ++i) { v[i] = __expf(v[i] - mx); sum += v[i]; }
        sum += __shfl_xor(sum, 16);
        sum += __shfl_xor(sum, 32);
        const float inv = 1.0f / sum;
        float* aout = out + CTX + ((long)b * 64 + hq * 16 + r16) * 64 + q * 16;
        #pragma unroll
        for (int i = 0; i < 16; ++i) aout[i] = v[i] * inv;
    }
}

// ---- kernel B: context = attn @ q ----
__global__ __launch_bounds__(256, 4)
void ovo_ctx(const float* __restrict__ qm, const float* __restrict__ out_attn,
             float* __restrict__ out)
{
    __shared__ __align__(16) _Float16 qT[2][64 * QTP];   // q^T chunk [e][g]  36 KB

    const int t = threadIdx.x, lane = t & 63, w = t >> 6;
    const int r16 = lane & 15, q = lane >> 4;
    const long b = blockIdx.x;
    const long base = b * 64 * 512;
    const float4_t zf4 = {0.f, 0.f, 0.f, 0.f};

    const float* ap = out_attn + (b * 64 + w * 16 + r16) * 64 + q * 8;
    half8_t pA0, pA1;
    {
        float4_t x = *(const float4_t*)(ap + 0),  y = *(const float4_t*)(ap + 4);
        pA0[0]=(_Float16)x[0]; pA0[1]=(_Float16)x[1]; pA0[2]=(_Float16)x[2]; pA0[3]=(_Float16)x[3];
        pA0[4]=(_Float16)y[0]; pA0[5]=(_Float16)y[1]; pA0[6]=(_Float16)y[2]; pA0[7]=(_Float16)y[3];
        float4_t z = *(const float4_t*)(ap + 32), u = *(const float4_t*)(ap + 36);
        pA1[0]=(_Float16)z[0]; pA1[1]=(_Float16)z[1]; pA1[2]=(_Float16)z[2]; pA1[3]=(_Float16)z[3];
        pA1[4]=(_Float16)u[0]; pA1[5]=(_Float16)u[1]; pA1[6]=(_Float16)u[2]; pA1[7]=(_Float16)u[3];
    }

    const int sg = t & 63, se = (t >> 6) * 16;
    const float* qsrc = qm + base + (long)sg * 512 + se;
    float4_t rA[4], rB[4];

    #define QLOAD(R, c) do { \
        _Pragma("unroll") \
        for (int i = 0; i < 4; ++i) R[i] = *(const float4_t*)(qsrc + (c) * 64 + i * 4); \
    } while (0)
    #define QCOMMIT(R, buf) do { \
        _Pragma("unroll") \
        for (int i = 0; i < 4; ++i) \
            _Pragma("unroll") \
            for (int jj = 0; jj < 4; ++jj) \
                qT[buf][(se + i * 4 + jj) * QTP + sg] = (_Float16)R[i][jj]; \
    } while (0)
    #define BCOMP(c, buf) do { \
        _Pragma("unroll") \
        for (int et = 0; et < 4; ++et) { \
            half8_t b0 = *(const half8_t*)(&qT[buf][(et * 16 + r16) * QTP + q * 8]); \
            half8_t b1 = *(const half8_t*)(&qT[buf][(et * 16 + r16) * QTP + 32 + q * 8]); \
            float4_t acc = MFMA32(pA0, b0, zf4); \
            acc = MFMA32(pA1, b1, acc); \
            _Pragma("unroll") \
            for (int rr = 0; rr < 4; ++rr) \
                out[(b * 64 + w * 16 + q * 4 + rr) * 512 + (c) * 64 + et * 16 + r16] = acc[rr]; \
        } \
    } while (0)

    QLOAD(rA, 0);
    QCOMMIT(rA, 0);
    __syncthreads();
    #pragma unroll
    for (int cc = 0; cc < 8; cc += 2) {
        QLOAD(rB, cc + 1);
        BCOMP(cc, 0);
        QCOMMIT(rB, 1);
        __syncthreads();
        if (cc + 2 < 8) QLOAD(rA, cc + 2);
        BCOMP(cc + 1, 1);
        if (cc + 2 < 8) QCOMMIT(rA, 0);
        __syncthreads();
    }
}

extern "C" void kernel_launch(void* const* d_in, const int* in_sizes, int n_in,
                              void* d_out, int out_size, void* d_ws, size_t ws_size,
                              hipStream_t stream) {
    const float* o1 = (const float*)d_in[0];
    const float* o2 = (const float*)d_in[1];
    const float* o3 = (const float*)d_in[2];
    const float* qm = (const float*)d_in[3];
    const float* W  = (const float*)d_in[4];
    float* out = (float*)d_out;
    _Float16* W2 = (_Float16*)d_ws;                 // 1 MB  fragment-layout fp16 W
    _Float16* V2 = (_Float16*)d_ws + V2OFF;         // 67 MB fragment-layout fp16 V

    w_pack<<<dim3(128), dim3(256), 0, stream>>>(W, W2);
    ovo_v<<<dim3(Bb), dim3(512), 0, stream>>>(qm, W2, V2);
    ovo_s<<<dim3(Bb * 4), dim3(256), 0, stream>>>(o1, o2, o3, V2, out);
    ovo_ctx<<<dim3(Bb), dim3(256), 0, stream>>>(qm, out + CTX, out);
}

// Round 14
// 238.404 us; speedup vs baseline: 1.4535x; 1.0868x over previous
//
#include <hip/hip_runtime.h>
#include <hip/hip_bf16.h>

typedef _Float16 half4_t __attribute__((ext_vector_type(4)));
typedef _Float16 half8_t __attribute__((ext_vector_type(8)));
typedef float    float4_t __attribute__((ext_vector_type(4)));

#define MFMA32(a, b, c) __builtin_amdgcn_mfma_f32_16x16x32_f16((a), (b), (c), 0, 0, 0)

constexpr int  Bb  = 1024;
constexpr long CTX = (long)Bb * 64 * 512;      // attn offset in d_out
constexpr int  SQP = 520;                      // sQ (q / V^T) row stride (halves)
constexpr int  SMP = 520;                      // sM row stride (halves)
constexpr int  AP  = 72;                       // sAttn row stride (halves)
constexpr long V2OFF = 524288;                 // V2 offset into ws (halves)
constexpr long Q2OFF = V2OFF + (long)Bb * 32768;   // q2 offset (halves)

// ---- pre-pass: pack W (f32 [e][f]) into fragment layout fp16 ----
// W2[(E*16+c)*512 + lane*8 + j] = W[E*16+(lane&15)][c*32+(lane>>4)*8+j]
__global__ void w_pack(const float* __restrict__ W, _Float16* __restrict__ W2) {
    const int t = blockIdx.x * 256 + threadIdx.x;      // 32768 threads
    const int lane = t & 63, grp = t >> 6;             // grp 0..511
    const int E = grp >> 4, c = grp & 15;
    const int r16 = lane & 15, q = lane >> 4;
    const float* src = W + (long)(E * 16 + r16) * 512 + c * 32 + q * 8;
    float4_t x = *(const float4_t*)(src);
    float4_t y = *(const float4_t*)(src + 4);
    half8_t h;
    h[0]=(_Float16)x[0]; h[1]=(_Float16)x[1]; h[2]=(_Float16)x[2]; h[3]=(_Float16)x[3];
    h[4]=(_Float16)y[0]; h[5]=(_Float16)y[1]; h[6]=(_Float16)y[2]; h[7]=(_Float16)y[3];
    *(half8_t*)(W2 + (long)t * 8) = h;
}

// ---- kernel V: stage q->LDS; emit q2 (ctx B-frag layout); V^T = q*W^T -> V2 ----
// V2[b][(gt*16+cc)*512 + lane*8 + j] = V^T[g=gt*16+(lane&15)][e=cc*32+(lane>>4)*8+j]
// q2[b][(et*2+cc)*512 + lane*8 + j]  = q  [g=cc*32+(lane>>4)*8+j][e=et*16+(lane&15)]
__global__ __launch_bounds__(512, 3)
void ovo_v(const float* __restrict__ qm, const _Float16* __restrict__ W2,
           _Float16* __restrict__ V2, _Float16* __restrict__ Q2)
{
    __shared__ __align__(16) _Float16 sQ[64 * SQP];   // q fp16, then V^T; 66.6 KB

    const int t = threadIdx.x, lane = t & 63, w = t >> 6;
    const int r16 = lane & 15, q = lane >> 4;
    const long base = (long)blockIdx.x * 64 * 512;
    const float4_t zf4 = {0.f, 0.f, 0.f, 0.f};

    // stage q fp16, flat-linear
    {
        const long qb = base + (long)t * 4;
        #pragma unroll
        for (int k = 0; k < 16; ++k) {
            float4_t v = *(const float4_t*)(qm + qb + (long)k * 2048);
            half4_t h;
            h[0]=(_Float16)v[0]; h[1]=(_Float16)v[1]; h[2]=(_Float16)v[2]; h[3]=(_Float16)v[3];
            *(half4_t*)(&sQ[(k * 4 + (t >> 7)) * SQP + (t & 127) * 4]) = h;
        }
    }
    __syncthreads();

    // q2 write (transposed-fragment layout for context B operand)
    {
        _Float16* q2dst = Q2 + (long)blockIdx.x * 32768;
        #pragma unroll
        for (int i = 0; i < 8; ++i) {
            const int grp = w * 8 + i;          // et*2 + cc
            const int et = grp >> 1, cc = grp & 1;
            half8_t hv;
            #pragma unroll
            for (int j = 0; j < 8; ++j)
                hv[j] = sQ[(cc * 32 + q * 8 + j) * SQP + et * 16 + r16];
            *(half8_t*)(q2dst + (long)grp * 512 + lane * 8) = hv;
        }
    }

    // V^T[g][e] = sum_f q[g,f]*W[e,f]; wave w owns e-slice [64w, 64w+64)
    float4_t vacc[4][4];   // [g2][et]
    #pragma unroll
    for (int i = 0; i < 4; ++i)
        #pragma unroll
        for (int j = 0; j < 4; ++j) vacc[i][j] = zf4;

    #pragma unroll
    for (int c = 0; c < 16; ++c) {
        half8_t Aq[4], Bw[4];
        #pragma unroll
        for (int g2 = 0; g2 < 4; ++g2)
            Aq[g2] = *(const half8_t*)(&sQ[(g2 * 16 + r16) * SQP + c * 32 + q * 8]);
        #pragma unroll
        for (int et = 0; et < 4; ++et)
            Bw[et] = *(const half8_t*)(W2 + (long)((w * 4 + et) * 16 + c) * 512 + lane * 8);
        #pragma unroll
        for (int g2 = 0; g2 < 4; ++g2)
            #pragma unroll
            for (int et = 0; et < 4; ++et)
                vacc[g2][et] = MFMA32(Aq[g2], Bw[et], vacc[g2][et]);
    }
    __syncthreads();                       // q dead (q2 written, GEMM done)

    #pragma unroll
    for (int g2 = 0; g2 < 4; ++g2)
        #pragma unroll
        for (int et = 0; et < 4; ++et)
            #pragma unroll
            for (int r = 0; r < 4; ++r)
                sQ[(g2 * 16 + q * 4 + r) * SQP + w * 64 + et * 16 + r16] =
                    (_Float16)vacc[g2][et][r];
    __syncthreads();

    _Float16* vdst = V2 + (long)blockIdx.x * 32768;
    #pragma unroll
    for (int i = 0; i < 8; ++i) {
        const int grp = w * 8 + i;              // 0..63 = gt*16 + cc
        const int gt = grp >> 4, cc = grp & 15;
        half8_t hv = *(const half8_t*)(&sQ[(gt * 16 + r16) * SQP + cc * 32 + q * 8]);
        *(half8_t*)(vdst + (long)grp * 512 + lane * 8) = hv;
    }
}

// ---- kernel SC: o-stage -> mean -> score -> softmax -> attn AND context ----
__global__ __launch_bounds__(256, 4)
void ovo_sc(const float* __restrict__ o1, const float* __restrict__ o2,
            const float* __restrict__ o3, const _Float16* __restrict__ V2,
            const _Float16* __restrict__ Q2, float* __restrict__ out)
{
    __shared__ __align__(16) _Float16 sM[16 * SMP];   // mean chunk fp16; 16.6 KB
    __shared__ float sRed[4][16 * 68];                // 17.4 KB partials
    __shared__ __align__(16) _Float16 sAttn[16 * AP]; // 2.3 KB attn fp16

    const int t = threadIdx.x, lane = t & 63, w = t >> 6;   // 4 waves = 4 e-slices
    const int r16 = lane & 15, q = lane >> 4;

    // XCD-chunked swizzle (V2/q2 L2 reuse: 4 hq-blocks of a batch co-resident)
    const int l = blockIdx.x;
    const int xcd = l & 7, m = l >> 3;
    const int b  = xcd * 128 + (m >> 2);
    const int hq = m & 3;

    const long cbase = (long)b * 32768 + (long)hq * 8192;   // floats
    const _Float16* vb  = V2 + (long)b * 32768;
    const _Float16* qb2 = Q2 + (long)b * 32768;
    const float4_t zf4 = {0.f, 0.f, 0.f, 0.f};

    // ---- linear stage: 1 KB-contiguous wave reads ----
    const float* p1 = o1 + cbase + t * 4;
    const float* p2 = o2 + cbase + t * 4;
    const float* p3 = o3 + cbase + t * 4;
    const int srow0 = t >> 7, scol = (t & 127) * 4;

    {
        float4_t A1[4], A2[4], A3[4];
        #pragma unroll
        for (int i = 0; i < 4; ++i) A1[i] = *(const float4_t*)(p1 + i * 1024);
        #pragma unroll
        for (int i = 0; i < 4; ++i) A2[i] = *(const float4_t*)(p2 + i * 1024);
        #pragma unroll
        for (int i = 0; i < 4; ++i) A3[i] = *(const float4_t*)(p3 + i * 1024);
        #pragma unroll
        for (int i = 0; i < 4; ++i) {
            float4_t mv = (A1[i] + A2[i] + A3[i]) * (1.0f / 3.0f);
            half4_t h;
            h[0]=(_Float16)mv[0]; h[1]=(_Float16)mv[1]; h[2]=(_Float16)mv[2]; h[3]=(_Float16)mv[3];
            *(half4_t*)(&sM[(i * 2 + srow0) * SMP + scol]) = h;
        }
        float4_t B1[4], B2[4], B3[4];
        #pragma unroll
        for (int i = 0; i < 4; ++i) B1[i] = *(const float4_t*)(p1 + (i + 4) * 1024);
        #pragma unroll
        for (int i = 0; i < 4; ++i) B2[i] = *(const float4_t*)(p2 + (i + 4) * 1024);
        #pragma unroll
        for (int i = 0; i < 4; ++i) B3[i] = *(const float4_t*)(p3 + (i + 4) * 1024);
        #pragma unroll
        for (int i = 0; i < 4; ++i) {
            float4_t mv = (B1[i] + B2[i] + B3[i]) * (1.0f / 3.0f);
            half4_t h;
            h[0]=(_Float16)mv[0]; h[1]=(_Float16)mv[1]; h[2]=(_Float16)mv[2]; h[3]=(_Float16)mv[3];
            *(half4_t*)(&sM[((i + 4) * 2 + srow0) * SMP + scol]) = h;
        }
    }
    __syncthreads();

    // ---- score: wave w owns e-slice [w*128, w*128+128) ----
    float4_t acc0 = zf4, acc1 = zf4, acc2 = zf4, acc3 = zf4;

    #define SCOMP(c) do { \
        half8_t af = *(const half8_t*)(&sM[r16 * SMP + w * 128 + (c) * 32 + q * 8]); \
        half8_t bf0 = *(const half8_t*)(vb + (long)( 0 + w * 4 + (c)) * 512 + lane * 8); \
        half8_t bf1 = *(const half8_t*)(vb + (long)(16 + w * 4 + (c)) * 512 + lane * 8); \
        half8_t bf2 = *(const half8_t*)(vb + (long)(32 + w * 4 + (c)) * 512 + lane * 8); \
        half8_t bf3 = *(const half8_t*)(vb + (long)(48 + w * 4 + (c)) * 512 + lane * 8); \
        acc0 = MFMA32(af, bf0, acc0); \
        acc1 = MFMA32(af, bf1, acc1); \
        acc2 = MFMA32(af, bf2, acc2); \
        acc3 = MFMA32(af, bf3, acc3); \
    } while (0)

    SCOMP(0); SCOMP(1); SCOMP(2); SCOMP(3);

    // partials: sRed[w][h*68 + g], h=(q*4+r), g=gt*16+r16
    #pragma unroll
    for (int r = 0; r < 4; ++r) {
        sRed[w][(q * 4 + r) * 68 +  0 + r16] = acc0[r];
        sRed[w][(q * 4 + r) * 68 + 16 + r16] = acc1[r];
        sRed[w][(q * 4 + r) * 68 + 32 + r16] = acc2[r];
        sRed[w][(q * 4 + r) * 68 + 48 + r16] = acc3[r];
    }
    __syncthreads();
    if (w == 0) {
        for (int i = 0; i < 17; ++i)
            sRed[0][lane + i * 64] += sRed[2][lane + i * 64];
    }
    if (w == 1) {
        for (int i = 0; i < 17; ++i)
            sRed[1][lane + i * 64] += sRed[3][lane + i * 64];
    }
    __syncthreads();
    if (w == 0) {
        for (int i = 0; i < 17; ++i)
            sRed[0][lane + i * 64] += sRed[1][lane + i * 64];
    }
    __syncthreads();

    // softmax over g (wave 0: 16 rows, 4 lanes/row); attn -> out + sAttn(fp16)
    if (w == 0) {
        const float* srow = &sRed[0][r16 * 68 + q * 16];
        float v[16];
        float mx = -1e30f;
        #pragma unroll
        for (int i = 0; i < 16; ++i) { v[i] = srow[i]; mx = fmaxf(mx, v[i]); }
        mx = fmaxf(mx, __shfl_xor(mx, 16));
        mx = fmaxf(mx, __shfl_xor(mx, 32));
        float sum = 0.f;
        #pragma unroll
        for (int i = 0; i < 16; ++i) { v[i] = __expf(v[i] - mx); sum += v[i]; }
        sum += __shfl_xor(sum, 16);
        sum += __shfl_xor(sum, 32);
        const float inv = 1.0f / sum;
        float* aout = out + CTX + ((long)b * 64 + hq * 16 + r16) * 64 + q * 16;
        #pragma unroll
        for (int i = 0; i < 16; ++i) {
            float a = v[i] * inv;
            aout[i] = a;
            sAttn[r16 * AP + q * 16 + i] = (_Float16)a;
        }
    }
    __syncthreads();

    // ---- context: ctx[h][e] = attn[h][:] @ q ; wave w owns e-tiles [w*8, w*8+8) ----
    {
        half8_t a0 = *(const half8_t*)(&sAttn[r16 * AP + q * 8]);        // k-chunk 0
        half8_t a1 = *(const half8_t*)(&sAttn[r16 * AP + 32 + q * 8]);   // k-chunk 1
        #pragma unroll
        for (int i = 0; i < 8; ++i) {
            const int et = w * 8 + i;
            half8_t b0 = *(const half8_t*)(qb2 + (long)(et * 2 + 0) * 512 + lane * 8);
            half8_t b1 = *(const half8_t*)(qb2 + (long)(et * 2 + 1) * 512 + lane * 8);
            float4_t acc = MFMA32(a0, b0, zf4);
            acc = MFMA32(a1, b1, acc);
            #pragma unroll
            for (int r = 0; r < 4; ++r)
                out[((long)b * 64 + hq * 16 + q * 4 + r) * 512 + et * 16 + r16] = acc[r];
        }
    }
}

extern "C" void kernel_launch(void* const* d_in, const int* in_sizes, int n_in,
                              void* d_out, int out_size, void* d_ws, size_t ws_size,
                              hipStream_t stream) {
    const float* o1 = (const float*)d_in[0];
    const float* o2 = (const float*)d_in[1];
    const float* o3 = (const float*)d_in[2];
    const float* qm = (const float*)d_in[3];
    const float* W  = (const float*)d_in[4];
    float* out = (float*)d_out;
    _Float16* W2 = (_Float16*)d_ws;                 // 1 MB  fragment-layout fp16 W
    _Float16* V2 = (_Float16*)d_ws + V2OFF;         // 67 MB fragment-layout fp16 V
    _Float16* Q2 = (_Float16*)d_ws + Q2OFF;         // 67 MB ctx-B-frag fp16 q

    w_pack<<<dim3(128), dim3(256), 0, stream>>>(W, W2);
    ovo_v<<<dim3(Bb), dim3(512), 0, stream>>>(qm, W2, V2, Q2);
    ovo_sc<<<dim3(Bb * 4), dim3(256), 0, stream>>>(o1, o2, o3, V2, Q2, out);
}